// Round 1
// baseline (798.849 us; speedup 1.0000x reference)
//
#include <hip/hip_runtime.h>
#include <math.h>

#define NND 50000
#define NE  800000
#define HID 128
#define NGR 32
#define NLAYER 4

static __device__ __forceinline__ unsigned fenc(float f){
  unsigned u = __float_as_uint(f);
  return (u & 0x80000000u) ? ~u : (u | 0x80000000u);
}
static __device__ __forceinline__ float fdec(unsigned u){
  return __uint_as_float((u & 0x80000000u) ? (u & 0x7fffffffu) : ~u);
}

// ---------------- CSR build ----------------
__global__ void k_count(const int* __restrict__ ei, int* __restrict__ cnt, int E, int N){
  int e = blockIdx.x * blockDim.x + threadIdx.x;
  if (e >= E + N) return;
  int dst = (e < E) ? ei[E + e] : (e - E);   // self-loops appended
  atomicAdd(&cnt[dst], 1);
}

__global__ __launch_bounds__(256) void k_scan(const int* __restrict__ cnt, int* __restrict__ off, int n){
  __shared__ int ps[256];
  int t = threadIdx.x;
  int chunk = (n + 255) / 256;
  int s0 = t * chunk, s1 = min(s0 + chunk, n);
  int s = 0;
  for (int i = s0; i < s1; ++i) s += cnt[i];
  ps[t] = s; __syncthreads();
  for (int o = 1; o < 256; o <<= 1){
    int v = (t >= o) ? ps[t - o] : 0;
    __syncthreads();
    ps[t] += v;
    __syncthreads();
  }
  int run = (t == 0) ? 0 : ps[t - 1];
  for (int i = s0; i < s1; ++i){ off[i] = run; run += cnt[i]; }
  if (s0 < n && s1 == n) off[n] = run;
}

__global__ void k_fill(const int* __restrict__ ei, const int* __restrict__ off,
                       int* __restrict__ cursor, int* __restrict__ csr_src, int E, int N){
  int e = blockIdx.x * blockDim.x + threadIdx.x;
  if (e >= E + N) return;
  int src, dst;
  if (e < E){ src = ei[e]; dst = ei[E + e]; } else { src = e - E; dst = e - E; }
  int pos = off[dst] + atomicAdd(&cursor[dst], 1);
  csr_src[pos] = src;
}

// ---------------- GEMM [N,128] @ [128,128] (+optional bias) ----------------
__global__ __launch_bounds__(256) void gemm128(const float* __restrict__ A,
    const float* __restrict__ W, const float* __restrict__ bias,
    float* __restrict__ out, int N)
{
  __shared__ float As[32][HID];
  int row0 = blockIdx.x * 32;
  int tid = threadIdx.x;
  const float4* A4 = (const float4*)A;
  float4* As4 = (float4*)(&As[0][0]);
  for (int i = tid; i < 32 * 32; i += 256) {
    int r = i >> 5;
    int gr = row0 + r;
    float4 v = make_float4(0.f, 0.f, 0.f, 0.f);
    if (gr < N) v = A4[(long)gr * 32 + (i & 31)];
    As4[i] = v;
  }
  __syncthreads();
  int tx = tid & 31, ty = tid >> 5;
  int r0 = ty * 4;
  float acc[4][4];
#pragma unroll
  for (int i = 0; i < 4; ++i)
#pragma unroll
    for (int j = 0; j < 4; ++j) acc[i][j] = 0.f;
  const float4* W4 = (const float4*)W;
#pragma unroll 4
  for (int k = 0; k < HID; ++k) {
    float4 w = W4[k * 32 + tx];
    float a0 = As[r0 + 0][k], a1 = As[r0 + 1][k], a2 = As[r0 + 2][k], a3 = As[r0 + 3][k];
    acc[0][0] += a0 * w.x; acc[0][1] += a0 * w.y; acc[0][2] += a0 * w.z; acc[0][3] += a0 * w.w;
    acc[1][0] += a1 * w.x; acc[1][1] += a1 * w.y; acc[1][2] += a1 * w.z; acc[1][3] += a1 * w.w;
    acc[2][0] += a2 * w.x; acc[2][1] += a2 * w.y; acc[2][2] += a2 * w.z; acc[2][3] += a2 * w.w;
    acc[3][0] += a3 * w.x; acc[3][1] += a3 * w.y; acc[3][2] += a3 * w.z; acc[3][3] += a3 * w.w;
  }
  float4 bb = make_float4(0.f, 0.f, 0.f, 0.f);
  if (bias) bb = ((const float4*)bias)[tx];
#pragma unroll
  for (int i = 0; i < 4; ++i) {
    int gr = row0 + r0 + i;
    if (gr < N) {
      float4 o = make_float4(acc[i][0] + bb.x, acc[i][1] + bb.y, acc[i][2] + bb.z, acc[i][3] + bb.w);
      ((float4*)out)[(long)gr * 32 + tx] = o;
    }
  }
}

// ---------------- per-node attention logits ----------------
__global__ __launch_bounds__(256) void k_esed(const float* __restrict__ hW,
    const float* __restrict__ a_s, const float* __restrict__ a_d,
    float* __restrict__ es, float* __restrict__ ed, int N)
{
  int w = threadIdx.x >> 6;
  int lane = threadIdx.x & 63;
  int n = blockIdx.x * 4 + w;
  if (n >= N) return;
  float2 v = ((const float2*)hW)[(long)n * 64 + lane];
  float ps = v.x * a_s[2 * lane] + v.y * a_s[2 * lane + 1];
  float pd = v.x * a_d[2 * lane] + v.y * a_d[2 * lane + 1];
#pragma unroll
  for (int o = 32; o; o >>= 1) { ps += __shfl_xor(ps, o); pd += __shfl_xor(pd, o); }
  if (lane == 0) { es[n] = ps; ed[n] = pd; }
}

// ---------------- fused edge softmax + aggregate + bias + LN + ELU + residual ----------------
__global__ __launch_bounds__(64) void edge_agg(
    const float* __restrict__ hW, const float* __restrict__ es, const float* __restrict__ ed,
    const int* __restrict__ off, const int* __restrict__ csr_src,
    const float* __restrict__ gb, const float* __restrict__ lg, const float* __restrict__ lb,
    const float* __restrict__ resid, float* __restrict__ hout, int do_elu)
{
  int dst = blockIdx.x;
  int lane = threadIdx.x;
  int b = off[dst], e = off[dst + 1];
  float edv = ed[dst];

  float m = -1e30f;
  for (int j = b + lane; j < e; j += 64) {
    float x = es[csr_src[j]] + edv;
    x = x > 0.f ? x : 0.2f * x;
    m = fmaxf(m, x);
  }
#pragma unroll
  for (int o = 32; o; o >>= 1) m = fmaxf(m, __shfl_xor(m, o));

  float z = 0.f;
  for (int j = b + lane; j < e; j += 64) {
    float x = es[csr_src[j]] + edv;
    x = x > 0.f ? x : 0.2f * x;
    z += __expf(x - m);
  }
#pragma unroll
  for (int o = 32; o; o >>= 1) z += __shfl_xor(z, o);
  float inv_z = 1.0f / z;

  __shared__ float s_a[64];
  __shared__ int   s_s[64];
  float2 acc = make_float2(0.f, 0.f);
  const float2* h2 = (const float2*)hW;
  for (int c0 = b; c0 < e; c0 += 64) {
    int j = c0 + lane;
    if (j < e) {
      int s = csr_src[j];
      float x = es[s] + edv;
      x = x > 0.f ? x : 0.2f * x;
      s_a[lane] = __expf(x - m) * inv_z;
      s_s[lane] = s;
    }
    __syncthreads();
    int cnt = min(64, e - c0);
    for (int t = 0; t < cnt; ++t) {
      float a = s_a[t];
      float2 hv = h2[(long)s_s[t] * 64 + lane];
      acc.x += a * hv.x;
      acc.y += a * hv.y;
    }
    __syncthreads();
  }

  float v0 = acc.x + gb[2 * lane];
  float v1 = acc.y + gb[2 * lane + 1];
  float s1 = v0 + v1, s2 = v0 * v0 + v1 * v1;
#pragma unroll
  for (int o = 32; o; o >>= 1) { s1 += __shfl_xor(s1, o); s2 += __shfl_xor(s2, o); }
  float mu = s1 * (1.f / 128.f);
  float var = s2 * (1.f / 128.f) - mu * mu;
  float rstd = rsqrtf(var + 1e-5f);
  float y0 = (v0 - mu) * rstd * lg[2 * lane] + lb[2 * lane];
  float y1 = (v1 - mu) * rstd * lg[2 * lane + 1] + lb[2 * lane + 1];
  if (do_elu) {
    y0 = y0 > 0.f ? y0 : expm1f(y0);
    y1 = y1 > 0.f ? y1 : expm1f(y1);
  }
  float2 r = ((const float2*)resid)[(long)dst * 64 + lane];
  ((float2*)hout)[(long)dst * 64 + lane] = make_float2(y0 + r.x, y1 + r.y);
}

// ---------------- pooling (mean + max per graph) ----------------
__global__ __launch_bounds__(128) void k_pool(const float* __restrict__ h, const int* __restrict__ batch,
    float* __restrict__ gsum, unsigned* __restrict__ gmax, int* __restrict__ gcnt, int N)
{
  int n0 = blockIdx.x * 64;
  int c = threadIdx.x;
  int cur = -1; float ls = 0.f, lm = -1e30f; int lc = 0;
  for (int i = 0; i < 64; ++i) {
    int n = n0 + i;
    if (n >= N) break;
    int g = batch[n];
    if (g != cur) {
      if (lc > 0) {
        atomicAdd(&gsum[cur * HID + c], ls);
        atomicMax(&gmax[cur * HID + c], fenc(lm));
        if (c == 0) atomicAdd(&gcnt[cur], lc);
      }
      cur = g; ls = 0.f; lm = -1e30f; lc = 0;
    }
    float v = h[(long)n * HID + c];
    ls += v; lm = fmaxf(lm, v); lc++;
  }
  if (lc > 0) {
    atomicAdd(&gsum[cur * HID + c], ls);
    atomicMax(&gmax[cur * HID + c], fenc(lm));
    if (c == 0) atomicAdd(&gcnt[cur], lc);
  }
}

// ---------------- final MLP, single block ----------------
__global__ __launch_bounds__(256) void k_mlp(const float* __restrict__ gsum,
    const unsigned* __restrict__ gmax, const int* __restrict__ gcnt,
    const float* __restrict__ W1, const float* __restrict__ b1,
    const float* __restrict__ W2, const float* __restrict__ b2,
    const float* __restrict__ W3, const float* __restrict__ b3,
    float* __restrict__ out)
{
  __shared__ float G[NGR * 256];
  __shared__ float O1[NGR * 128];
  __shared__ float O2[NGR * 64];
  int tid = threadIdx.x;
  for (int idx = tid; idx < NGR * 256; idx += 256) {
    int r = idx >> 8, c = idx & 255;
    float v;
    if (c < 128) v = gsum[r * HID + c] / fmaxf((float)gcnt[r], 1.0f);
    else v = fdec(gmax[r * HID + (c - 128)]);
    G[idx] = v;
  }
  __syncthreads();
  {
    int c = tid & 127, rg = tid >> 7;   // 2 groups of 16 rows
    float acc[16];
#pragma unroll
    for (int r = 0; r < 16; ++r) acc[r] = 0.f;
    for (int k = 0; k < 256; ++k) {
      float w = W1[k * 128 + c];
#pragma unroll
      for (int r = 0; r < 16; ++r) acc[r] += G[(rg * 16 + r) * 256 + k] * w;
    }
#pragma unroll
    for (int r = 0; r < 16; ++r) {
      float v = acc[r] + b1[c];
      O1[(rg * 16 + r) * 128 + c] = v > 0.f ? v : 0.f;
    }
  }
  __syncthreads();
  {
    int c = tid & 63, rg = tid >> 6;    // 4 groups of 8 rows
    float acc[8];
#pragma unroll
    for (int r = 0; r < 8; ++r) acc[r] = 0.f;
    for (int k = 0; k < 128; ++k) {
      float w = W2[k * 64 + c];
#pragma unroll
      for (int r = 0; r < 8; ++r) acc[r] += O1[(rg * 8 + r) * 128 + k] * w;
    }
#pragma unroll
    for (int r = 0; r < 8; ++r) {
      float v = acc[r] + b2[c];
      O2[(rg * 8 + r) * 64 + c] = v > 0.f ? v : 0.f;
    }
  }
  __syncthreads();
  if (tid < NGR * 4) {
    int r = tid >> 2, c = tid & 3;
    float a = 0.f;
    for (int k = 0; k < 64; ++k) a += O2[r * 64 + k] * W3[k * 4 + c];
    out[r * 4 + c] = a + b3[c];
  }
}

extern "C" void kernel_launch(void* const* d_in, const int* in_sizes, int n_in,
                              void* d_out, int out_size, void* d_ws, size_t ws_size,
                              hipStream_t stream) {
  const float* x      = (const float*)d_in[0];
  const int*   ei     = (const int*)d_in[1];
  const int*   batch  = (const int*)d_in[2];
  const float* Ws     = (const float*)d_in[3];
  const float* a_src  = (const float*)d_in[4];
  const float* a_dst  = (const float*)d_in[5];
  const float* gat_b  = (const float*)d_in[6];
  const float* ln_g   = (const float*)d_in[7];
  const float* ln_b   = (const float*)d_in[8];
  const float* skip_W = (const float*)d_in[9];
  const float* skip_b = (const float*)d_in[10];
  const float* W1     = (const float*)d_in[11];
  const float* b1     = (const float*)d_in[12];
  const float* W2     = (const float*)d_in[13];
  const float* b2     = (const float*)d_in[14];
  const float* W3     = (const float*)d_in[15];
  const float* b3     = (const float*)d_in[16];
  float* out = (float*)d_out;

  const int N = NND, E = NE;

  char* p = (char*)d_ws;
  auto alloc = [&](size_t bytes) -> void* {
    void* r = (void*)p;
    p += (bytes + 255) & ~(size_t)255;
    return r;
  };
  float* skip   = (float*)alloc(sizeof(float) * (size_t)N * HID);
  float* hcur   = (float*)alloc(sizeof(float) * (size_t)N * HID);
  float* hW     = (float*)alloc(sizeof(float) * (size_t)N * HID);
  float* es     = (float*)alloc(sizeof(float) * N);
  float* ed     = (float*)alloc(sizeof(float) * N);
  int*   cnt    = (int*)alloc(sizeof(int) * N);          // also reused as cursor
  int*   off    = (int*)alloc(sizeof(int) * (N + 1));
  int*   csr    = (int*)alloc(sizeof(int) * (E + N));
  char*  zbeg   = p;
  float* gsum   = (float*)alloc(sizeof(float) * NGR * HID);
  unsigned* gmax = (unsigned*)alloc(sizeof(unsigned) * NGR * HID);
  int*   gcnt   = (int*)alloc(sizeof(int) * NGR);
  size_t zlen = (size_t)(p - zbeg);

  // ---- CSR build ----
  hipMemsetAsync(cnt, 0, sizeof(int) * N, stream);
  int tot = E + N;
  k_count<<<(tot + 255) / 256, 256, 0, stream>>>(ei, cnt, E, N);
  k_scan<<<1, 256, 0, stream>>>(cnt, off, N);
  hipMemsetAsync(cnt, 0, sizeof(int) * N, stream);
  k_fill<<<(tot + 255) / 256, 256, 0, stream>>>(ei, off, cnt, csr, E, N);

  // ---- skip projection ----
  int gblocks = (N + 31) / 32;
  gemm128<<<gblocks, 256, 0, stream>>>(x, skip_W, skip_b, skip, N);

  // ---- layers ----
  for (int l = 0; l < NLAYER; ++l) {
    const float* input = (l == 0) ? x : hcur;
    const float* resid = (l == 0) ? skip : hcur;
    gemm128<<<gblocks, 256, 0, stream>>>(input, Ws + (size_t)l * HID * HID, nullptr, hW, N);
    k_esed<<<(N + 3) / 4, 256, 0, stream>>>(hW, a_src + l * HID, a_dst + l * HID, es, ed, N);
    edge_agg<<<N, 64, 0, stream>>>(hW, es, ed, off, csr,
                                   gat_b + l * HID, ln_g + l * HID, ln_b + l * HID,
                                   resid, hcur, (l < NLAYER - 1) ? 1 : 0);
  }

  // ---- pooling + MLP ----
  hipMemsetAsync(zbeg, 0, zlen, stream);
  k_pool<<<(N + 63) / 64, 128, 0, stream>>>(hcur, batch, gsum, gmax, gcnt, N);
  k_mlp<<<1, 256, 0, stream>>>(gsum, gmax, gcnt, W1, b1, W2, b2, W3, b3, out);
}

// Round 2
// 693.252 us; speedup vs baseline: 1.1523x; 1.1523x over previous
//
#include <hip/hip_runtime.h>
#include <math.h>

#define NND 50000
#define NE  800000
#define HID 128
#define NGR 32
#define NLAYER 4

static __device__ __forceinline__ unsigned fenc(float f){
  unsigned u = __float_as_uint(f);
  return (u & 0x80000000u) ? ~u : (u | 0x80000000u);
}
static __device__ __forceinline__ float fdec(unsigned u){
  return __uint_as_float((u & 0x80000000u) ? (u & 0x7fffffffu) : ~u);
}

// ---------------- CSR build ----------------
__global__ void k_count(const int* __restrict__ ei, int* __restrict__ cnt, int E, int N){
  int e = blockIdx.x * blockDim.x + threadIdx.x;
  if (e >= E + N) return;
  int dst = (e < E) ? ei[E + e] : (e - E);   // self-loops appended
  atomicAdd(&cnt[dst], 1);
}

// hierarchical scan: per-block sums -> scan of block sums -> per-block offsets
__global__ __launch_bounds__(256) void k_bsum(const int* __restrict__ cnt, int* __restrict__ bsum, int n){
  int i = blockIdx.x * 256 + threadIdx.x;
  int v = (i < n) ? cnt[i] : 0;
#pragma unroll
  for (int o = 32; o; o >>= 1) v += __shfl_down(v, o);
  __shared__ int s[4];
  int lane = threadIdx.x & 63, wid = threadIdx.x >> 6;
  if (lane == 0) s[wid] = v;
  __syncthreads();
  if (threadIdx.x == 0) bsum[blockIdx.x] = s[0] + s[1] + s[2] + s[3];
}

__global__ __launch_bounds__(256) void k_scanb(int* __restrict__ bsum, int nb){
  __shared__ int ps[256];
  int t = threadIdx.x;
  int v = (t < nb) ? bsum[t] : 0;
  ps[t] = v; __syncthreads();
  for (int o = 1; o < 256; o <<= 1){
    int u = (t >= o) ? ps[t - o] : 0;
    __syncthreads();
    ps[t] += u;
    __syncthreads();
  }
  if (t < nb) bsum[t] = ps[t] - v;  // exclusive
}

__global__ __launch_bounds__(256) void k_off(const int* __restrict__ cnt, const int* __restrict__ bsum,
                                             int* __restrict__ off, int n){
  __shared__ int ps[256];
  int t = threadIdx.x;
  int i = blockIdx.x * 256 + t;
  int v = (i < n) ? cnt[i] : 0;
  ps[t] = v; __syncthreads();
  for (int o = 1; o < 256; o <<= 1){
    int u = (t >= o) ? ps[t - o] : 0;
    __syncthreads();
    ps[t] += u;
    __syncthreads();
  }
  int excl = ps[t] - v + bsum[blockIdx.x];
  if (i < n) off[i] = excl;
  if (i == n - 1) off[n] = excl + v;
}

__global__ void k_fill(const int* __restrict__ ei, const int* __restrict__ off,
                       int* __restrict__ cursor, int* __restrict__ csr_src, int E, int N){
  int e = blockIdx.x * blockDim.x + threadIdx.x;
  if (e >= E + N) return;
  int src, dst;
  if (e < E){ src = ei[e]; dst = ei[E + e]; } else { src = e - E; dst = e - E; }
  int pos = off[dst] + atomicAdd(&cursor[dst], 1);
  csr_src[pos] = src;
}

// ---------------- GEMM [N,128] @ [128,128] (+bias, + fused es/ed epilogue) ----------------
__global__ __launch_bounds__(256) void gemm128(const float* __restrict__ A,
    const float* __restrict__ W, const float* __restrict__ bias,
    const float* __restrict__ a_s, const float* __restrict__ a_d,
    float* __restrict__ out, float* __restrict__ es, float* __restrict__ ed, int N)
{
  __shared__ float As[32][HID];
  int row0 = blockIdx.x * 32;
  int tid = threadIdx.x;
  const float4* A4 = (const float4*)A;
  float4* As4 = (float4*)(&As[0][0]);
  for (int i = tid; i < 32 * 32; i += 256) {
    int r = i >> 5;
    int gr = row0 + r;
    float4 v = make_float4(0.f, 0.f, 0.f, 0.f);
    if (gr < N) v = A4[(long)gr * 32 + (i & 31)];
    As4[i] = v;
  }
  __syncthreads();
  int tx = tid & 31, ty = tid >> 5;
  int r0 = ty * 4;
  float acc[4][4];
#pragma unroll
  for (int i = 0; i < 4; ++i)
#pragma unroll
    for (int j = 0; j < 4; ++j) acc[i][j] = 0.f;
  const float4* W4 = (const float4*)W;
#pragma unroll 4
  for (int k = 0; k < HID; ++k) {
    float4 w = W4[k * 32 + tx];
    float a0 = As[r0 + 0][k], a1 = As[r0 + 1][k], a2 = As[r0 + 2][k], a3 = As[r0 + 3][k];
    acc[0][0] += a0 * w.x; acc[0][1] += a0 * w.y; acc[0][2] += a0 * w.z; acc[0][3] += a0 * w.w;
    acc[1][0] += a1 * w.x; acc[1][1] += a1 * w.y; acc[1][2] += a1 * w.z; acc[1][3] += a1 * w.w;
    acc[2][0] += a2 * w.x; acc[2][1] += a2 * w.y; acc[2][2] += a2 * w.z; acc[2][3] += a2 * w.w;
    acc[3][0] += a3 * w.x; acc[3][1] += a3 * w.y; acc[3][2] += a3 * w.z; acc[3][3] += a3 * w.w;
  }
  float4 bb = make_float4(0.f, 0.f, 0.f, 0.f);
  if (bias) bb = ((const float4*)bias)[tx];
#pragma unroll
  for (int i = 0; i < 4; ++i) {
    int gr = row0 + r0 + i;
    if (gr < N) {
      float4 o = make_float4(acc[i][0] + bb.x, acc[i][1] + bb.y, acc[i][2] + bb.z, acc[i][3] + bb.w);
      ((float4*)out)[(long)gr * 32 + tx] = o;
    }
  }
  if (a_s) {
    // fused per-row attention logits: es[r] = h[r]·a_s, ed[r] = h[r]·a_d
    float4 as4 = ((const float4*)a_s)[tx];
    float4 ad4 = ((const float4*)a_d)[tx];
#pragma unroll
    for (int i = 0; i < 4; ++i) {
      float s_ = acc[i][0] * as4.x + acc[i][1] * as4.y + acc[i][2] * as4.z + acc[i][3] * as4.w;
      float d_ = acc[i][0] * ad4.x + acc[i][1] * ad4.y + acc[i][2] * ad4.z + acc[i][3] * ad4.w;
#pragma unroll
      for (int o = 16; o; o >>= 1) { s_ += __shfl_xor(s_, o); d_ += __shfl_xor(d_, o); }
      int gr = row0 + r0 + i;
      if (tx == 0 && gr < N) { es[gr] = s_; ed[gr] = d_; }
    }
  }
}

// ---------------- fused edge softmax + aggregate + bias + LN + ELU + residual ----------------
__global__ __launch_bounds__(64) void edge_agg(
    const float* __restrict__ hW, const float* __restrict__ es, const float* __restrict__ ed,
    const int* __restrict__ off, const int* __restrict__ csr_src,
    const float* __restrict__ gb, const float* __restrict__ lg, const float* __restrict__ lb,
    const float* __restrict__ resid, float* __restrict__ hout, int do_elu)
{
  int dst = blockIdx.x;
  int lane = threadIdx.x;
  int b = off[dst], e = off[dst + 1];
  float edv = ed[dst];

  float m = -1e30f;
  for (int j = b + lane; j < e; j += 64) {
    float x = es[csr_src[j]] + edv;
    x = x > 0.f ? x : 0.2f * x;
    m = fmaxf(m, x);
  }
#pragma unroll
  for (int o = 32; o; o >>= 1) m = fmaxf(m, __shfl_xor(m, o));

  float z = 0.f;
  for (int j = b + lane; j < e; j += 64) {
    float x = es[csr_src[j]] + edv;
    x = x > 0.f ? x : 0.2f * x;
    z += __expf(x - m);
  }
#pragma unroll
  for (int o = 32; o; o >>= 1) z += __shfl_xor(z, o);
  float inv_z = 1.0f / z;

  __shared__ float s_a[64];
  __shared__ int   s_s[64];
  float2 acc = make_float2(0.f, 0.f);
  const float2* h2 = (const float2*)hW;
  for (int c0 = b; c0 < e; c0 += 64) {
    int j = c0 + lane;
    if (j < e) {
      int s = csr_src[j];
      float x = es[s] + edv;
      x = x > 0.f ? x : 0.2f * x;
      s_a[lane] = __expf(x - m) * inv_z;
      s_s[lane] = s;
    }
    __syncthreads();
    int cnt = min(64, e - c0);
#pragma unroll 4
    for (int t = 0; t < cnt; ++t) {
      float a = s_a[t];
      float2 hv = h2[(long)s_s[t] * 64 + lane];
      acc.x += a * hv.x;
      acc.y += a * hv.y;
    }
    __syncthreads();
  }

  float v0 = acc.x + gb[2 * lane];
  float v1 = acc.y + gb[2 * lane + 1];
  float s1 = v0 + v1, s2 = v0 * v0 + v1 * v1;
#pragma unroll
  for (int o = 32; o; o >>= 1) { s1 += __shfl_xor(s1, o); s2 += __shfl_xor(s2, o); }
  float mu = s1 * (1.f / 128.f);
  float var = s2 * (1.f / 128.f) - mu * mu;
  float rstd = rsqrtf(var + 1e-5f);
  float y0 = (v0 - mu) * rstd * lg[2 * lane] + lb[2 * lane];
  float y1 = (v1 - mu) * rstd * lg[2 * lane + 1] + lb[2 * lane + 1];
  if (do_elu) {
    y0 = y0 > 0.f ? y0 : expm1f(y0);
    y1 = y1 > 0.f ? y1 : expm1f(y1);
  }
  float2 r = ((const float2*)resid)[(long)dst * 64 + lane];
  ((float2*)hout)[(long)dst * 64 + lane] = make_float2(y0 + r.x, y1 + r.y);
}

// ---------------- pooling (mean + max per graph) ----------------
__global__ __launch_bounds__(128) void k_pool(const float* __restrict__ h, const int* __restrict__ batch,
    float* __restrict__ gsum, unsigned* __restrict__ gmax, int* __restrict__ gcnt, int N)
{
  int n0 = blockIdx.x * 64;
  int c = threadIdx.x;
  int cur = -1; float ls = 0.f, lm = -1e30f; int lc = 0;
  for (int i = 0; i < 64; ++i) {
    int n = n0 + i;
    if (n >= N) break;
    int g = batch[n];
    if (g != cur) {
      if (lc > 0) {
        atomicAdd(&gsum[cur * HID + c], ls);
        atomicMax(&gmax[cur * HID + c], fenc(lm));
        if (c == 0) atomicAdd(&gcnt[cur], lc);
      }
      cur = g; ls = 0.f; lm = -1e30f; lc = 0;
    }
    float v = h[(long)n * HID + c];
    ls += v; lm = fmaxf(lm, v); lc++;
  }
  if (lc > 0) {
    atomicAdd(&gsum[cur * HID + c], ls);
    atomicMax(&gmax[cur * HID + c], fenc(lm));
    if (c == 0) atomicAdd(&gcnt[cur], lc);
  }
}

// ---------------- final MLP, single block ----------------
__global__ __launch_bounds__(256) void k_mlp(const float* __restrict__ gsum,
    const unsigned* __restrict__ gmax, const int* __restrict__ gcnt,
    const float* __restrict__ W1, const float* __restrict__ b1,
    const float* __restrict__ W2, const float* __restrict__ b2,
    const float* __restrict__ W3, const float* __restrict__ b3,
    float* __restrict__ out)
{
  __shared__ float G[NGR * 256];
  __shared__ float O1[NGR * 128];
  __shared__ float O2[NGR * 64];
  int tid = threadIdx.x;
  for (int idx = tid; idx < NGR * 256; idx += 256) {
    int r = idx >> 8, c = idx & 255;
    float v;
    if (c < 128) v = gsum[r * HID + c] / fmaxf((float)gcnt[r], 1.0f);
    else v = fdec(gmax[r * HID + (c - 128)]);
    G[idx] = v;
  }
  __syncthreads();
  {
    int c = tid & 127, rg = tid >> 7;   // 2 groups of 16 rows
    float acc[16];
#pragma unroll
    for (int r = 0; r < 16; ++r) acc[r] = 0.f;
    for (int k = 0; k < 256; ++k) {
      float w = W1[k * 128 + c];
#pragma unroll
      for (int r = 0; r < 16; ++r) acc[r] += G[(rg * 16 + r) * 256 + k] * w;
    }
#pragma unroll
    for (int r = 0; r < 16; ++r) {
      float v = acc[r] + b1[c];
      O1[(rg * 16 + r) * 128 + c] = v > 0.f ? v : 0.f;
    }
  }
  __syncthreads();
  {
    int c = tid & 63, rg = tid >> 6;    // 4 groups of 8 rows
    float acc[8];
#pragma unroll
    for (int r = 0; r < 8; ++r) acc[r] = 0.f;
    for (int k = 0; k < 128; ++k) {
      float w = W2[k * 64 + c];
#pragma unroll
      for (int r = 0; r < 8; ++r) acc[r] += O1[(rg * 8 + r) * 128 + k] * w;
    }
#pragma unroll
    for (int r = 0; r < 8; ++r) {
      float v = acc[r] + b2[c];
      O2[(rg * 8 + r) * 64 + c] = v > 0.f ? v : 0.f;
    }
  }
  __syncthreads();
  if (tid < NGR * 4) {
    int r = tid >> 2, c = tid & 3;
    float a = 0.f;
    for (int k = 0; k < 64; ++k) a += O2[r * 64 + k] * W3[k * 4 + c];
    out[r * 4 + c] = a + b3[c];
  }
}

extern "C" void kernel_launch(void* const* d_in, const int* in_sizes, int n_in,
                              void* d_out, int out_size, void* d_ws, size_t ws_size,
                              hipStream_t stream) {
  const float* x      = (const float*)d_in[0];
  const int*   ei     = (const int*)d_in[1];
  const int*   batch  = (const int*)d_in[2];
  const float* Ws     = (const float*)d_in[3];
  const float* a_src  = (const float*)d_in[4];
  const float* a_dst  = (const float*)d_in[5];
  const float* gat_b  = (const float*)d_in[6];
  const float* ln_g   = (const float*)d_in[7];
  const float* ln_b   = (const float*)d_in[8];
  const float* skip_W = (const float*)d_in[9];
  const float* skip_b = (const float*)d_in[10];
  const float* W1     = (const float*)d_in[11];
  const float* b1     = (const float*)d_in[12];
  const float* W2     = (const float*)d_in[13];
  const float* b2     = (const float*)d_in[14];
  const float* W3     = (const float*)d_in[15];
  const float* b3     = (const float*)d_in[16];
  float* out = (float*)d_out;

  const int N = NND, E = NE;
  const int NB = (N + 255) / 256;   // 196 scan blocks

  char* p = (char*)d_ws;
  auto alloc = [&](size_t bytes) -> void* {
    void* r = (void*)p;
    p += (bytes + 255) & ~(size_t)255;
    return r;
  };
  float* skip   = (float*)alloc(sizeof(float) * (size_t)N * HID);
  float* hcur   = (float*)alloc(sizeof(float) * (size_t)N * HID);
  float* hW     = (float*)alloc(sizeof(float) * (size_t)N * HID);
  float* es     = (float*)alloc(sizeof(float) * N);
  float* ed     = (float*)alloc(sizeof(float) * N);
  int*   cnt    = (int*)alloc(sizeof(int) * N);          // also reused as cursor
  int*   off    = (int*)alloc(sizeof(int) * (N + 1));
  int*   csr    = (int*)alloc(sizeof(int) * (E + N));
  int*   bsum   = (int*)alloc(sizeof(int) * NB);
  char*  zbeg   = p;
  float* gsum   = (float*)alloc(sizeof(float) * NGR * HID);
  unsigned* gmax = (unsigned*)alloc(sizeof(unsigned) * NGR * HID);
  int*   gcnt   = (int*)alloc(sizeof(int) * NGR);
  size_t zlen = (size_t)(p - zbeg);

  // ---- CSR build ----
  hipMemsetAsync(cnt, 0, sizeof(int) * N, stream);
  int tot = E + N;
  k_count<<<(tot + 255) / 256, 256, 0, stream>>>(ei, cnt, E, N);
  k_bsum<<<NB, 256, 0, stream>>>(cnt, bsum, N);
  k_scanb<<<1, 256, 0, stream>>>(bsum, NB);
  k_off<<<NB, 256, 0, stream>>>(cnt, bsum, off, N);
  hipMemsetAsync(cnt, 0, sizeof(int) * N, stream);
  k_fill<<<(tot + 255) / 256, 256, 0, stream>>>(ei, off, cnt, csr, E, N);

  // ---- skip projection ----
  int gblocks = (N + 31) / 32;
  gemm128<<<gblocks, 256, 0, stream>>>(x, skip_W, skip_b, nullptr, nullptr, skip, nullptr, nullptr, N);

  // ---- layers ----
  for (int l = 0; l < NLAYER; ++l) {
    const float* input = (l == 0) ? x : hcur;
    const float* resid = (l == 0) ? skip : hcur;
    gemm128<<<gblocks, 256, 0, stream>>>(input, Ws + (size_t)l * HID * HID, nullptr,
                                         a_src + l * HID, a_dst + l * HID, hW, es, ed, N);
    edge_agg<<<N, 64, 0, stream>>>(hW, es, ed, off, csr,
                                   gat_b + l * HID, ln_g + l * HID, ln_b + l * HID,
                                   resid, hcur, (l < NLAYER - 1) ? 1 : 0);
  }

  // ---- pooling + MLP ----
  hipMemsetAsync(zbeg, 0, zlen, stream);
  k_pool<<<(N + 63) / 64, 128, 0, stream>>>(hcur, batch, gsum, gmax, gcnt, N);
  k_mlp<<<1, 256, 0, stream>>>(gsum, gmax, gcnt, W1, b1, W2, b2, W3, b3, out);
}